// Round 2
// baseline (707.900 us; speedup 1.0000x reference)
//
#include <hip/hip_runtime.h>
#include <cstdint>
#include <cstddef>

#define K_PAD 4128  // 4097 padded up to a multiple of 32 (zeros contribute 0)
#define BKg 32
#define NT 129      // K_PAD / BKg

typedef __bf16 bf16x8 __attribute__((ext_vector_type(8)));
typedef float f32x4 __attribute__((ext_vector_type(4)));

__device__ __forceinline__ unsigned short f2bf(float f) {
  // round-to-nearest-even fp32 -> bf16
  unsigned int u = __float_as_uint(f);
  u = (u + 0x7fffu + ((u >> 16) & 1u)) >> 16;
  return (unsigned short)u;
}

__device__ __forceinline__ void gload_lds16(const void* g, void* l) {
  __builtin_amdgcn_global_load_lds((const __attribute__((address_space(1))) void*)g,
                                   (__attribute__((address_space(3))) void*)l,
                                   16, 0, 0);
}

// x (8192x4096 f32) -> xa (8192x4128 bf16): cols 0..4095 = x, col 4096 = 1.0, 4097.. = 0
__global__ void k_xaug(const float* __restrict__ x, unsigned short* __restrict__ xa) {
  const int row = blockIdx.x;
  const int t = threadIdx.x;
  const float4* xr = (const float4*)(x + (size_t)row * 4096);
  unsigned short* out = xa + (size_t)row * K_PAD;
#pragma unroll
  for (int i = 0; i < 4; ++i) {
    const int g = t + i * 256;  // float4 group within row, 0..1023
    float4 v = xr[g];
    ushort4 o;
    o.x = f2bf(v.x); o.y = f2bf(v.y); o.z = f2bf(v.z); o.w = f2bf(v.w);
    *(ushort4*)(out + g * 4) = o;
  }
  if (t < 32) out[4096 + t] = (t == 0) ? (unsigned short)0x3F80 : (unsigned short)0;
}

// weights = q_mu + exp(q_ls)*eps -> bf16 (4096x4128, padded cols zero)
// kl summed elementwise, one atomicAdd per block. float4-vectorized main body.
__global__ void k_wkl(const float* __restrict__ q_mu, const float* __restrict__ q_ls,
                      const float* __restrict__ p_mu, const float* __restrict__ eps,
                      const float* __restrict__ p_ls, unsigned short* __restrict__ w,
                      float* __restrict__ kl_out) {
  const int row = blockIdx.x;   // 4096 rows
  const int t = threadIdx.x;    // 256 threads
  const float pls = p_ls[0];
  const float inv2ps2 = 0.5f * __expf(-2.0f * pls);  // 1/(2*p_sigma^2)
  const size_t base = (size_t)row * 4097;
  unsigned short* wr = w + (size_t)row * K_PAD;
  float kl = 0.f;
  const float4* qm4 = (const float4*)(q_mu + base);
  const float4* ql4 = (const float4*)(q_ls + base);
  const float4* pm4 = (const float4*)(p_mu + base);
  const float4* ep4 = (const float4*)(eps + base);
  if ((((size_t)row * 4097) & 3) == 0) {
#pragma unroll 1
    for (int i = 0; i < 4; ++i) {
      const int g = t + i * 256;  // float4 group 0..1023 covers cols 0..4095
      float4 qm = qm4[g], ql = ql4[g], pm = pm4[g], ep = ep4[g];
      float kls = 0.f;
      ushort4 o;
      {
        float qs = __expf(ql.x); float d = pm.x - qm.x;
        kls += (pls - ql.x) - 0.5f + (qs * qs + d * d) * inv2ps2;
        o.x = f2bf(__fmaf_rn(qs, ep.x, qm.x));
      }
      {
        float qs = __expf(ql.y); float d = pm.y - qm.y;
        kls += (pls - ql.y) - 0.5f + (qs * qs + d * d) * inv2ps2;
        o.y = f2bf(__fmaf_rn(qs, ep.y, qm.y));
      }
      {
        float qs = __expf(ql.z); float d = pm.z - qm.z;
        kls += (pls - ql.z) - 0.5f + (qs * qs + d * d) * inv2ps2;
        o.z = f2bf(__fmaf_rn(qs, ep.z, qm.z));
      }
      {
        float qs = __expf(ql.w); float d = pm.w - qm.w;
        kls += (pls - ql.w) - 0.5f + (qs * qs + d * d) * inv2ps2;
        o.w = f2bf(__fmaf_rn(qs, ep.w, qm.w));
      }
      kl += kls;
      *(ushort4*)(wr + g * 4) = o;
    }
    if (t == 0) {
      const int c = 4096;
      float qm = q_mu[base + c], ql = q_ls[base + c];
      float qs = __expf(ql);
      float d = p_mu[base + c] - qm;
      kl += (pls - ql) - 0.5f + (qs * qs + d * d) * inv2ps2;
      wr[c] = f2bf(__fmaf_rn(qs, eps[base + c], qm));
    }
    if (t < 31) wr[4097 + t] = 0;
  } else {
#pragma unroll 1
    for (int i = 0; i < 17; ++i) {
      const int c = t + i * 256;
      if (c < 4097) {
        float qm = q_mu[base + c];
        float ql = q_ls[base + c];
        float qs = __expf(ql);
        float e  = eps[base + c];
        float pm = p_mu[base + c];
        float d = pm - qm;
        kl += (pls - ql) - 0.5f + (qs * qs + d * d) * inv2ps2;
        wr[c] = f2bf(__fmaf_rn(qs, e, qm));
      } else if (c < K_PAD) {
        wr[c] = 0;
      }
    }
  }
#pragma unroll
  for (int off = 32; off > 0; off >>= 1) kl += __shfl_down(kl, off, 64);
  __shared__ float part[4];
  const int wave = t >> 6, lane = t & 63;
  if (lane == 0) part[wave] = kl;
  __syncthreads();
  if (t == 0) atomicAdd(kl_out, part[0] + part[1] + part[2] + part[3]);
}

// C(8192x4096 f32) = A(8192xK_PAD bf16) * B^T, B = (4096xK_PAD bf16), both K-contiguous.
// 256x256 tile, BK=32, 8 waves (2Mx4N) each owning 128x64, mfma_f32_16x16x32_bf16.
// 3-deep LDS ring (96 KB): iteration kt computes from slot kt%3 while issuing
// global_load_lds staging for tile kt+2 into slot (kt+2)%3 (last read finished
// before the barrier ending iteration kt-1 -> race-free). One raw s_barrier +
// counted s_waitcnt vmcnt(4) per K-step; vmcnt never drains to 0 in the loop
// (T3/T4), so prefetch stays in flight across barriers. setprio(1) wraps MFMA
// clusters (T5). LDS XOR-swizzle carried over verbatim from the verified 128²
// kernel: 16B chunk for (row r, kgroup kgv) lives at chunk index
// r*4 + (kgv ^ ((r>>1)&3)); staging pre-permutes the GLOBAL source per lane.
__global__ __launch_bounds__(512, 2) void k_gemm(const unsigned short* __restrict__ A,
                                                 const unsigned short* __restrict__ Bm,
                                                 float* __restrict__ C) {
  __shared__ unsigned short As[3][256 * 32];
  __shared__ unsigned short Bs[3][256 * 32];
  const int t = threadIdx.x;     // 0..511
  const int wave = t >> 6;       // 0..7
  const int lane = t & 63;
  const int wm = wave >> 2;      // 0..1  (M half: 128 rows)
  const int wn = wave & 3;       // 0..3  (N quarter: 64 cols)
  const int rowBase = blockIdx.y * 256;
  const int colBase = blockIdx.x * 256;
  const int fr = lane & 15;      // fragment row within 16
  const int kg = lane >> 4;      // k-group (8 bf16 each), 0..3

  f32x4 acc[8][4] = {};

  const unsigned short* Abase = A + (size_t)rowBase * K_PAD;
  const unsigned short* Bbase = Bm + (size_t)colBase * K_PAD;

  // staging: thread t fills LDS chunk c = s*512 + t (s in {0,1}); chunk holds
  // global (row r = c>>2 = s*128 + (t>>2), kg_src = (t&3) ^ ((t>>3)&3))
  const int rs = t >> 2;                              // row for s=0; s=1 adds 128
  const int kc = ((t & 3) ^ ((t >> 3) & 3)) * 8;      // bf16 col of the 16B chunk
  const int lds0 = (wave * 64) * 8;                   // wave-uniform LDS base, s=0
  const int lds1 = (512 + wave * 64) * 8;             // s=1

  // fragment LDS chunk offsets (elements) — loop-invariant, swizzled
  int aOff[8], bOff[4];
#pragma unroll
  for (int i = 0; i < 8; ++i) {
    const int ra = wm * 128 + i * 16 + fr;
    aOff[i] = (ra * 4 + (kg ^ ((ra >> 1) & 3))) * 8;
  }
#pragma unroll
  for (int j = 0; j < 4; ++j) {
    const int rbr = wn * 64 + j * 16 + fr;
    bOff[j] = (rbr * 4 + (kg ^ ((rbr >> 1) & 3))) * 8;
  }

#define STAGE(SB, K0)                                                              \
  do {                                                                             \
    gload_lds16(Abase + (size_t)rs * K_PAD + (K0) + kc, &As[SB][lds0]);            \
    gload_lds16(Abase + (size_t)(rs + 128) * K_PAD + (K0) + kc, &As[SB][lds1]);    \
    gload_lds16(Bbase + (size_t)rs * K_PAD + (K0) + kc, &Bs[SB][lds0]);            \
    gload_lds16(Bbase + (size_t)(rs + 128) * K_PAD + (K0) + kc, &Bs[SB][lds1]);    \
  } while (0)

  // prologue: tiles 0 and 1 in flight; wait tile 0 resident (4 newest may fly)
  STAGE(0, 0);
  STAGE(1, BKg);
  asm volatile("s_waitcnt vmcnt(4)" ::: "memory");
  __builtin_amdgcn_s_barrier();
  asm volatile("" ::: "memory");

#define BODY(RB, SB, KT)                                                           \
  do {                                                                             \
    int kn = (KT) + 2; if (kn > NT - 1) kn = NT - 1; /* clamp: dup-stage tail */   \
    STAGE(SB, kn * BKg);                                                           \
    bf16x8 af[4], bfv[4];                                                          \
    _Pragma("unroll") for (int j = 0; j < 4; ++j)                                  \
      bfv[j] = *(const bf16x8*)&Bs[RB][bOff[j]];                                   \
    _Pragma("unroll") for (int i = 0; i < 4; ++i)                                  \
      af[i] = *(const bf16x8*)&As[RB][aOff[i]];                                    \
    __builtin_amdgcn_s_setprio(1);                                                 \
    _Pragma("unroll") for (int i = 0; i < 4; ++i)                                  \
      _Pragma("unroll") for (int j = 0; j < 4; ++j)                                \
        acc[i][j] = __builtin_amdgcn_mfma_f32_16x16x32_bf16(af[i], bfv[j],         \
                                                            acc[i][j], 0, 0, 0);  \
    __builtin_amdgcn_s_setprio(0);                                                 \
    _Pragma("unroll") for (int i = 0; i < 4; ++i)                                  \
      af[i] = *(const bf16x8*)&As[RB][aOff[4 + i]];                                \
    __builtin_amdgcn_s_setprio(1);                                                 \
    _Pragma("unroll") for (int i = 0; i < 4; ++i)                                  \
      _Pragma("unroll") for (int j = 0; j < 4; ++j)                                \
        acc[4 + i][j] = __builtin_amdgcn_mfma_f32_16x16x32_bf16(af[i], bfv[j],     \
                                                                acc[4 + i][j],    \
                                                                0, 0, 0);          \
    __builtin_amdgcn_s_setprio(0);                                                 \
    asm volatile("s_waitcnt vmcnt(4)" ::: "memory"); /* tile KT+1 resident */      \
    __builtin_amdgcn_s_barrier();                                                  \
    asm volatile("" ::: "memory");                                                 \
  } while (0)

  // 129 = 3*43 K-steps: unroll x3 so ring indices are compile-time
#pragma unroll 1
  for (int kt = 0; kt < NT; kt += 3) {
    BODY(0, 2, kt);
    BODY(1, 0, kt + 1);
    BODY(2, 1, kt + 2);
  }

#undef BODY
#undef STAGE

  // C/D layout: col = lane&15, row = (lane>>4)*4 + reg
  const int cr = (lane >> 4) * 4;
  const int cc = lane & 15;
#pragma unroll
  for (int i = 0; i < 8; ++i) {
#pragma unroll
    for (int j = 0; j < 4; ++j) {
      const int col = colBase + wn * 64 + j * 16 + cc;
#pragma unroll
      for (int r = 0; r < 4; ++r) {
        const int row = rowBase + wm * 128 + i * 16 + cr + r;
        C[(size_t)row * 4096 + col] = acc[i][j][r];
      }
    }
  }
}

extern "C" void kernel_launch(void* const* d_in, const int* in_sizes, int n_in,
                              void* d_out, int out_size, void* d_ws, size_t ws_size,
                              hipStream_t stream) {
  const float* x      = (const float*)d_in[0];
  const float* p_ls   = (const float*)d_in[1];
  const float* q_mu   = (const float*)d_in[2];
  const float* q_lsig = (const float*)d_in[3];
  const float* p_mu   = (const float*)d_in[4];
  const float* eps    = (const float*)d_in[5];
  float* out = (float*)d_out;
  float* kl_out = out + (size_t)8192 * 4096;

  // ws layout: x_aug bf16 (8192*4128 = 67.6MB), weights bf16 (4096*4128 = 33.8MB)
  unsigned short* xa   = (unsigned short*)d_ws;
  unsigned short* wmat = xa + (size_t)8192 * K_PAD;

  hipMemsetAsync(kl_out, 0, sizeof(float), stream);
  k_xaug<<<8192, 256, 0, stream>>>(x, xa);
  k_wkl<<<4096, 256, 0, stream>>>(q_mu, q_lsig, p_mu, eps, p_ls, wmat, kl_out);
  k_gemm<<<dim3(16, 32), 512, 0, stream>>>(xa, wmat, out);
}

// Round 3
// 628.342 us; speedup vs baseline: 1.1266x; 1.1266x over previous
//
#include <hip/hip_runtime.h>
#include <cstdint>
#include <cstddef>

#define K_PAD 4160  // 4097 padded up to a multiple of 64 (zeros contribute 0)
#define NT 65       // K-tiles of 64

typedef __bf16 bf16x8 __attribute__((ext_vector_type(8)));
typedef float f32x4 __attribute__((ext_vector_type(4)));

__device__ __forceinline__ unsigned short f2bf(float f) {
  unsigned int u = __float_as_uint(f);
  u = (u + 0x7fffu + ((u >> 16) & 1u)) >> 16;
  return (unsigned short)u;
}

__device__ __forceinline__ void gload_lds16(const void* g, void* l) {
  __builtin_amdgcn_global_load_lds((const __attribute__((address_space(1))) void*)g,
                                   (__attribute__((address_space(3))) void*)l,
                                   16, 0, 0);
}

// x (8192x4096 f32) -> xa (8192x4160 bf16): cols 0..4095 = x, col 4096 = 1.0, rest 0
__global__ void k_xaug(const float* __restrict__ x, unsigned short* __restrict__ xa) {
  const int row = blockIdx.x;
  const int t = threadIdx.x;
  const float4* xr = (const float4*)(x + (size_t)row * 4096);
  unsigned short* out = xa + (size_t)row * K_PAD;
#pragma unroll
  for (int i = 0; i < 4; ++i) {
    const int g = t + i * 256;
    float4 v = xr[g];
    ushort4 o;
    o.x = f2bf(v.x); o.y = f2bf(v.y); o.z = f2bf(v.z); o.w = f2bf(v.w);
    *(ushort4*)(out + g * 4) = o;
  }
  if (t < 64) out[4096 + t] = (t == 0) ? (unsigned short)0x3F80 : (unsigned short)0;
}

// weights = q_mu + exp(q_ls)*eps -> bf16 (4096x4160 padded); kl elementwise sum.
// FLAT indexing: 4096*4097 = 16781312 elems = 4195328 float4 groups = 4097 blocks
// x 256 thr x 4 groups, exactly. All float4 loads 16B-aligned (f % 4 == 0 always).
// row = f/4097 via magic (m=33546242, s=37: exact for f < 2^36), col = f - row*4097.
__global__ void k_wkl(const float* __restrict__ q_mu, const float* __restrict__ q_ls,
                      const float* __restrict__ p_mu, const float* __restrict__ eps,
                      const float* __restrict__ p_ls, unsigned short* __restrict__ w,
                      float* __restrict__ kl_out) {
  const int b = blockIdx.x;   // 0..4096
  const int t = threadIdx.x;  // 256
  const float pls = p_ls[0];
  const float inv2ps2 = 0.5f * __expf(-2.0f * pls);
  float kl = 0.f;
  // fold the row-pad zeroing (cols 4097..4159) into blocks 0..4095
  if (b < 4096 && t < 63) w[(size_t)b * K_PAD + 4097 + t] = 0;
#pragma unroll 1
  for (int i = 0; i < 4; ++i) {
    const unsigned g = (unsigned)b * 1024u + (unsigned)i * 256u + (unsigned)t;
    const unsigned f = g * 4u;
    const float4 qm = *(const float4*)(q_mu + f);
    const float4 ql = *(const float4*)(q_ls + f);
    const float4 pm = *(const float4*)(p_mu + f);
    const float4 ep = *(const float4*)(eps + f);
    unsigned short o[4];
    {
      float qs = __expf(ql.x); float d = pm.x - qm.x;
      kl += (pls - ql.x) - 0.5f + (qs * qs + d * d) * inv2ps2;
      o[0] = f2bf(__fmaf_rn(qs, ep.x, qm.x));
    }
    {
      float qs = __expf(ql.y); float d = pm.y - qm.y;
      kl += (pls - ql.y) - 0.5f + (qs * qs + d * d) * inv2ps2;
      o[1] = f2bf(__fmaf_rn(qs, ep.y, qm.y));
    }
    {
      float qs = __expf(ql.z); float d = pm.z - qm.z;
      kl += (pls - ql.z) - 0.5f + (qs * qs + d * d) * inv2ps2;
      o[2] = f2bf(__fmaf_rn(qs, ep.z, qm.z));
    }
    {
      float qs = __expf(ql.w); float d = pm.w - qm.w;
      kl += (pls - ql.w) - 0.5f + (qs * qs + d * d) * inv2ps2;
      o[3] = f2bf(__fmaf_rn(qs, ep.w, qm.w));
    }
    unsigned row = (unsigned)(((unsigned long long)f * 33546242ull) >> 37);
    unsigned col = f - row * 4097u;
#pragma unroll
    for (int e = 0; e < 4; ++e) {
      w[(size_t)row * K_PAD + col] = o[e];
      if (++col == 4097u) { col = 0; ++row; }
    }
  }
#pragma unroll
  for (int off = 32; off > 0; off >>= 1) kl += __shfl_down(kl, off, 64);
  __shared__ float part[4];
  const int wave = t >> 6, lane = t & 63;
  if (lane == 0) part[wave] = kl;
  __syncthreads();
  if (t == 0) atomicAdd(kl_out, part[0] + part[1] + part[2] + part[3]);
}

// C(8192x4096 f32) = A(8192xK_PAD bf16) * B^T, B = (4096xK_PAD bf16).
// 256x256 tile, BK=64, 8 waves (2Mx4N) each 128x64. 4 phases per K-tile (8-phase/
// 2-tile template, T3+T4+T5): per phase {asm ds_read_b128 subtile | stage |
// s_barrier | lgkmcnt(0)+sched_barrier | setprio1 + 16 MFMA + setprio0 | s_barrier}.
// 2-slot LDS dbuf (128KB); tile t read from slot t&1 while tile t+2 staged into the
// SAME slot: B at ph3 (B reads retired end-ph2), A at ph4 (A reads retired end-ph3).
// vmcnt(8) once per tile (leaves t+2's 8 loads in flight; per-wave drain + barrier
// => block-wide residency of tile t+1). Tail tiles dup-stage tile 64 (identical
// bytes -> benign). LDS XOR swizzle: chunk(row,c) at row*8 + (c ^ (row&7)); since
// row&7 == fr&7 for all fragments, reads collapse to 4 addr VGPRs + offset: imms.
__global__ __launch_bounds__(512, 2) void k_gemm(const unsigned short* __restrict__ A,
                                                 const unsigned short* __restrict__ Bm,
                                                 float* __restrict__ C) {
  __shared__ unsigned short As[2][256 * 64];
  __shared__ unsigned short Bs[2][256 * 64];
  const int t = threadIdx.x;     // 0..511
  const int wave = t >> 6;
  const int lane = t & 63;
  const int wm = wave >> 2;      // 0..1
  const int wn = wave & 3;       // 0..3
  const int rowBase = blockIdx.y * 256;
  const int colBase = blockIdx.x * 256;
  const int fr = lane & 15;
  const int kg = lane >> 4;      // 0..3

  f32x4 acc[8][4] = {};
  bf16x8 aA[2][4];  // [ks][i] current A half-quadrant rows
  bf16x8 bF[2][4];  // [ks][j] all B fragments of the tile

  // fragment LDS byte addresses (row&7 == fr&7 for every fragment row)
  const unsigned colx0 = (((unsigned)kg) ^ ((unsigned)fr & 7u)) * 16u;
  const unsigned colx1 = (((unsigned)kg + 4u) ^ ((unsigned)fr & 7u)) * 16u;
  const unsigned aLds = (unsigned)(uintptr_t)&As[0][0];
  const unsigned bLds = (unsigned)(uintptr_t)&Bs[0][0];
  const unsigned aAddr0 = aLds + (unsigned)(wm * 128 + fr) * 128u + colx0;
  const unsigned aAddr1 = aLds + (unsigned)(wm * 128 + fr) * 128u + colx1;
  const unsigned bAddr0 = bLds + (unsigned)(wn * 64 + fr) * 128u + colx0;
  const unsigned bAddr1 = bLds + (unsigned)(wn * 64 + fr) * 128u + colx1;

  // staging: thread t -> LDS chunk (q*512 + t), global row q*64 + (t>>3),
  // global col chunk (t&7) ^ ((t>>3)&7)   [inverse of the read swizzle]
  const unsigned gcol8 = (((unsigned)t & 7u) ^ (((unsigned)t >> 3) & 7u)) * 8u;
  const unsigned short* Asrc = A + (size_t)(rowBase + (t >> 3)) * K_PAD + gcol8;
  const unsigned short* Bsrc = Bm + (size_t)(colBase + (t >> 3)) * K_PAD + gcol8;

#define DSR_O(dst, addr, OFS) \
  asm volatile("ds_read_b128 %0, %1 offset:" OFS : "=v"(dst) : "v"(addr))
#define BAR __builtin_amdgcn_s_barrier()
#define LGKM0                                             \
  do {                                                    \
    asm volatile("s_waitcnt lgkmcnt(0)" ::: "memory");    \
    __builtin_amdgcn_sched_barrier(0);                    \
  } while (0)
#define VM8 asm volatile("s_waitcnt vmcnt(8)" ::: "memory")

#define STAGE(DST, S, SRC, KB)                                                  \
  do {                                                                          \
    gload_lds16((SRC) + (KB),                 &DST[S][0 * 4096 + wave * 512]);  \
    gload_lds16((SRC) + (KB) + 64 * K_PAD,    &DST[S][1 * 4096 + wave * 512]);  \
    gload_lds16((SRC) + (KB) + 128 * K_PAD,   &DST[S][2 * 4096 + wave * 512]);  \
    gload_lds16((SRC) + (KB) + 192 * K_PAD,   &DST[S][3 * 4096 + wave * 512]);  \
  } while (0)

#define MMQ(IB, JB)                                                             \
  do {                                                                          \
    _Pragma("unroll") for (int i_ = 0; i_ < 4; ++i_) {                          \
      _Pragma("unroll") for (int j_ = 0; j_ < 2; ++j_) {                        \
        acc[(IB) + i_][(JB) + j_] = __builtin_amdgcn_mfma_f32_16x16x32_bf16(    \
            aA[0][i_], bF[0][(JB) + j_], acc[(IB) + i_][(JB) + j_], 0, 0, 0);   \
        acc[(IB) + i_][(JB) + j_] = __builtin_amdgcn_mfma_f32_16x16x32_bf16(    \
            aA[1][i_], bF[1][(JB) + j_], acc[(IB) + i_][(JB) + j_], 0, 0, 0);   \
      }                                                                         \
    }                                                                           \
  } while (0)

#define TILE(S, T)                                                              \
  do {                                                                          \
    const int kn_ = ((T) + 2 > NT - 1) ? (NT - 1) : ((T) + 2);                  \
    const size_t kb_ = (size_t)kn_ * 64;                                        \
    const unsigned aS0 = aAddr0 + (S) * 32768u, aS1 = aAddr1 + (S) * 32768u;    \
    const unsigned bS0 = bAddr0 + (S) * 32768u, bS1 = bAddr1 + (S) * 32768u;    \
    /* ph1: A rows 0..63 (both ks) + B cols 0..31 */                            \
    DSR_O(aA[0][0], aS0, "0");    DSR_O(aA[0][1], aS0, "2048");                 \
    DSR_O(aA[0][2], aS0, "4096"); DSR_O(aA[0][3], aS0, "6144");                 \
    DSR_O(aA[1][0], aS1, "0");    DSR_O(aA[1][1], aS1, "2048");                 \
    DSR_O(aA[1][2], aS1, "4096"); DSR_O(aA[1][3], aS1, "6144");                 \
    DSR_O(bF[0][0], bS0, "0");    DSR_O(bF[0][1], bS0, "2048");                 \
    DSR_O(bF[1][0], bS1, "0");    DSR_O(bF[1][1], bS1, "2048");                 \
    BAR; LGKM0;                                                                 \
    __builtin_amdgcn_s_setprio(1); MMQ(0, 0); __builtin_amdgcn_s_setprio(0);    \
    BAR;                                                                        \
    /* ph2: B cols 32..63 */                                                    \
    DSR_O(bF[0][2], bS0, "4096"); DSR_O(bF[0][3], bS0, "6144");                 \
    DSR_O(bF[1][2], bS1, "4096"); DSR_O(bF[1][3], bS1, "6144");                 \
    BAR; LGKM0;                                                                 \
    __builtin_amdgcn_s_setprio(1); MMQ(0, 2); __builtin_amdgcn_s_setprio(0);    \
    BAR;                                                                        \
    /* ph3: A rows 64..127 + stage B(t+2) (B(t) reads retired end-ph2) */       \
    DSR_O(aA[0][0], aS0, "8192");  DSR_O(aA[0][1], aS0, "10240");               \
    DSR_O(aA[0][2], aS0, "12288"); DSR_O(aA[0][3], aS0, "14336");               \
    DSR_O(aA[1][0], aS1, "8192");  DSR_O(aA[1][1], aS1, "10240");               \
    DSR_O(aA[1][2], aS1, "12288"); DSR_O(aA[1][3], aS1, "14336");               \
    STAGE(Bs, S, Bsrc, kb_);                                                    \
    BAR; LGKM0;                                                                 \
    __builtin_amdgcn_s_setprio(1); MMQ(4, 0); __builtin_amdgcn_s_setprio(0);    \
    BAR;                                                                        \
    /* ph4: stage A(t+2) (A(t) reads retired end-ph3); drain to 8 */            \
    STAGE(As, S, Asrc, kb_);                                                    \
    BAR;                                                                        \
    __builtin_amdgcn_s_setprio(1); MMQ(4, 2); __builtin_amdgcn_s_setprio(0);    \
    VM8; BAR;                                                                   \
  } while (0)

  // prologue: tiles 0,1 staged; drain to 8 => tile 0 resident (tile 1 in flight)
  STAGE(Bs, 0, Bsrc, 0);
  STAGE(As, 0, Asrc, 0);
  STAGE(Bs, 1, Bsrc, 64);
  STAGE(As, 1, Asrc, 64);
  VM8; BAR;

#pragma unroll 1
  for (int tp = 0; tp < 32; ++tp) {
    TILE(0, 2 * tp);
    TILE(1, 2 * tp + 1);
  }
  TILE(0, 64);

#undef TILE
#undef MMQ
#undef STAGE
#undef VM8
#undef LGKM0
#undef BAR
#undef DSR_O

  // C/D layout: col = lane&15, row = (lane>>4)*4 + reg
  const int cr = (lane >> 4) * 4;
  const int cc = lane & 15;
#pragma unroll
  for (int i = 0; i < 8; ++i) {
#pragma unroll
    for (int j = 0; j < 4; ++j) {
      const int col = colBase + wn * 64 + j * 16 + cc;
#pragma unroll
      for (int r = 0; r < 4; ++r) {
        const int row = rowBase + wm * 128 + i * 16 + cr + r;
        C[(size_t)row * 4096 + col] = acc[i][j][r];
      }
    }
  }
}

extern "C" void kernel_launch(void* const* d_in, const int* in_sizes, int n_in,
                              void* d_out, int out_size, void* d_ws, size_t ws_size,
                              hipStream_t stream) {
  const float* x      = (const float*)d_in[0];
  const float* p_ls   = (const float*)d_in[1];
  const float* q_mu   = (const float*)d_in[2];
  const float* q_lsig = (const float*)d_in[3];
  const float* p_mu   = (const float*)d_in[4];
  const float* eps    = (const float*)d_in[5];
  float* out = (float*)d_out;
  float* kl_out = out + (size_t)8192 * 4096;

  // ws: x_aug bf16 (8192*4160 = 68.2MB), weights bf16 (4096*4160 = 34.1MB)
  unsigned short* xa   = (unsigned short*)d_ws;
  unsigned short* wmat = xa + (size_t)8192 * K_PAD;

  hipMemsetAsync(kl_out, 0, sizeof(float), stream);
  k_xaug<<<8192, 256, 0, stream>>>(x, xa);
  k_wkl<<<4097, 256, 0, stream>>>(q_mu, q_lsig, p_mu, eps, p_ls, wmat, kl_out);
  k_gemm<<<dim3(16, 32), 512, 0, stream>>>(xa, wmat, out);
}